// Round 3
// baseline (465.819 us; speedup 1.0000x reference)
//
#include <hip/hip_runtime.h>
#include <stdint.h>

#define O_FEATS 28672
#define I_FEATS 8192
#define BATCH 8
#define WPR 2048    // packed int32 words per output row (I/4); only low byte used
#define NTILES 1792 // 28672 / 16 rows per tile
#define GRID 512    // persistent: exactly 2 blocks/CU on 256 CUs

// ---------------------------------------------------------------------------
// Workspace layout (uint32 word indices into ws):
//   ws[0]        : final absmax (float bits, >= 1e-5), written by k_quant
//   ws[16..79]   : per-block absmax partials (64 blocks of k_absmax)
//   ws[128..191] : per-block sum_x partials, index = b*8 + seg
//   ws[1024..]   : x_q int8 [8][8192] (64 KB)
// ---------------------------------------------------------------------------

#if __has_builtin(__builtin_amdgcn_sdot4)
#define DOT4(a, b, c) __builtin_amdgcn_sdot4((a), (b), (c), false)
#else
static __device__ __forceinline__ int dot4_sw(int a, int b, int c) {
  c += (int)(signed char)(a & 0xff) * (int)(signed char)(b & 0xff);
  c += (int)(signed char)((a >> 8) & 0xff) * (int)(signed char)((b >> 8) & 0xff);
  c += (int)(signed char)((a >> 16) & 0xff) * (int)(signed char)((b >> 16) & 0xff);
  c += (int)(signed char)((a >> 24) & 0xff) * (int)(signed char)((b >> 24) & 0xff);
  return c;
}
#define DOT4(a, b, c) dot4_sw((a), (b), (c))
#endif

// Carry-free unpack of 4 ternary codes (bits [7:0] of p) to 4 unsigned bytes.
static __device__ __forceinline__ uint32_t unpack4(uint32_t p) {
  uint32_t lo = p & 0x0Fu;
  uint32_t hi = (p >> 4) & 0x0Fu;
  uint32_t a = (lo * 0x41u) & 0x0303u;
  uint32_t b = (hi * 0x41u) & 0x0303u;
  return a | (b << 16);
}

// 64 blocks x 256 threads x 4 floats = 65536 elements; per-block partial max.
__global__ void k_absmax(const float* __restrict__ x, uint32_t* __restrict__ ws) {
  __shared__ float red[4];
  int t = threadIdx.x;
  float4 v = ((const float4*)x)[blockIdx.x * 256 + t];
  float m = fmaxf(fmaxf(fabsf(v.x), fabsf(v.y)), fmaxf(fabsf(v.z), fabsf(v.w)));
#pragma unroll
  for (int off = 32; off; off >>= 1)
    m = fmaxf(m, __shfl_xor(m, off));
  if ((t & 63) == 0) red[t >> 6] = m;
  __syncthreads();
  if (t == 0)
    ws[16 + blockIdx.x] =
        __float_as_uint(fmaxf(fmaxf(red[0], red[1]), fmaxf(red[2], red[3])));
}

// 64 blocks: block (b = blk>>3, seg = blk&7) quantizes 1024 elems of row b.
__global__ void k_quant(const float* __restrict__ x, uint32_t* __restrict__ ws) {
  __shared__ float s_amax;
  __shared__ int reds[4];
  int b = blockIdx.x >> 3, seg = blockIdx.x & 7;
  int t = threadIdx.x;
  if (t < 64) {  // reduce the 64 absmax partials (all blocks redundantly)
    float m = __uint_as_float(ws[16 + t]);
#pragma unroll
    for (int off = 32; off; off >>= 1)
      m = fmaxf(m, __shfl_xor(m, off));
    if (t == 0) {
      float a = fmaxf(m, 1e-5f);
      s_amax = a;
      ws[0] = __float_as_uint(a);  // same value from every block: benign
    }
  }
  __syncthreads();
  float s = s_amax / 127.0f;  // match ref: x / (absmax/127)
  float4 v = ((const float4*)(x + b * I_FEATS + seg * 1024))[t];
  int q0 = (int)fminf(fmaxf(rintf(v.x / s), -128.f), 127.f);
  int q1 = (int)fminf(fmaxf(rintf(v.y / s), -128.f), 127.f);
  int q2 = (int)fminf(fmaxf(rintf(v.z / s), -128.f), 127.f);
  int q3 = (int)fminf(fmaxf(rintf(v.w / s), -128.f), 127.f);
  uint32_t pk = (uint32_t)(q0 & 0xff) | ((uint32_t)(q1 & 0xff) << 8) |
                ((uint32_t)(q2 & 0xff) << 16) | ((uint32_t)(q3 & 0xff) << 24);
  ws[1024 + b * 2048 + seg * 256 + t] = pk;
  int s4 = q0 + q1 + q2 + q3;
#pragma unroll
  for (int off = 32; off; off >>= 1)
    s4 += __shfl_xor(s4, off);
  if ((t & 63) == 0) reds[t >> 6] = s4;
  __syncthreads();
  if (t == 0)
    ws[128 + blockIdx.x] = (uint32_t)(reds[0] + reds[1] + reds[2] + reds[3]);
}

// Persistent GEMM: 512 blocks x 256 thr, each block walks tiles of 16 rows
// (tile = blockIdx, +512, ...). Wave -> 4 rows; lane l, iter j owns packed
// chunk c = j*64+l (16 weights = 16B int4 load, coalesced 1KB/wave/row).
__global__ void __launch_bounds__(256, 2)
k_gemm(const int* __restrict__ Wp, const float* __restrict__ wscale,
       const float* __restrict__ bias, const uint32_t* __restrict__ ws,
       float* __restrict__ out) {
  __shared__ uint32_t xq_lds[BATCH * 2048];  // 64 KB: x_q int8 [8][8192]
  __shared__ uint32_t lut[256];              // packed byte -> 4 code bytes
  __shared__ int s_sumx[BATCH];
  __shared__ float s_scale;

  int t = threadIdx.x;
  {  // stage x_q global(ws) -> LDS, 4096 int4 across 256 threads
    const int4* src = (const int4*)(ws + 1024);
    int4* dst = (int4*)xq_lds;
#pragma unroll
    for (int i = 0; i < 16; ++i) dst[t + 256 * i] = src[t + 256 * i];
  }
  lut[t] = unpack4((uint32_t)t);
  if (t < 64) {  // reduce 64 sum_x partials: index = b*8+seg -> xor over seg
    int p = (int)ws[128 + t];
    p += __shfl_xor(p, 1);
    p += __shfl_xor(p, 2);
    p += __shfl_xor(p, 4);
    if ((t & 7) == 0) s_sumx[t >> 3] = p;
  }
  if (t == 0) s_scale = (__uint_as_float(ws[0]) / 127.0f) * wscale[0];
  __syncthreads();

  const int wave = t >> 6, lane = t & 63;

  int tiles[4];
  int ntile = 0;
  for (int tt = blockIdx.x; tt < NTILES; tt += GRID) tiles[ntile++] = tt;

  int4 wcur[4], wnxt[4];
  {
    const int* wp0 = Wp + (tiles[0] * 16 + wave * 4) * WPR + 4 * lane;
#pragma unroll
    for (int oo = 0; oo < 4; ++oo) wcur[oo] = *(const int4*)(wp0 + oo * WPR);
  }

  for (int nt = 0; nt < ntile; ++nt) {
    const int o_base = tiles[nt] * 16 + wave * 4;
    const int* wp = Wp + o_base * WPR;

    int acc[4][8];
#pragma unroll
    for (int oo = 0; oo < 4; ++oo)
#pragma unroll
      for (int b = 0; b < 8; ++b) acc[oo][b] = 0;

#pragma unroll
    for (int j = 0; j < 8; ++j) {
      const int cc = j * 64 + lane;
      if (j < 7) {
#pragma unroll
        for (int oo = 0; oo < 4; ++oo)
          wnxt[oo] = *(const int4*)(wp + oo * WPR + 4 * (cc + 64));
      } else if (nt + 1 < ntile) {  // bridge: next tile's j=0 chunk
        const int* wpn = Wp + (tiles[nt + 1] * 16 + wave * 4) * WPR + 4 * lane;
#pragma unroll
        for (int oo = 0; oo < 4; ++oo) wnxt[oo] = *(const int4*)(wpn + oo * WPR);
      }
      // unpack via LDS LUT: each packed word's low byte -> 4 code bytes
      int code[4][4];
#pragma unroll
      for (int oo = 0; oo < 4; ++oo) {
        const uint32_t* pw = (const uint32_t*)&wcur[oo];
#pragma unroll
        for (int m = 0; m < 4; ++m) code[oo][m] = (int)lut[pw[m] & 0xFFu];
      }
#pragma unroll
      for (int b = 0; b < 8; ++b) {
        int4 xv = *(const int4*)&xq_lds[b * 2048 + 4 * cc];
#pragma unroll
        for (int oo = 0; oo < 4; ++oo) {
          acc[oo][b] = DOT4(code[oo][0], xv.x, acc[oo][b]);
          acc[oo][b] = DOT4(code[oo][1], xv.y, acc[oo][b]);
          acc[oo][b] = DOT4(code[oo][2], xv.z, acc[oo][b]);
          acc[oo][b] = DOT4(code[oo][3], xv.w, acc[oo][b]);
        }
      }
#pragma unroll
      for (int oo = 0; oo < 4; ++oo) wcur[oo] = wnxt[oo];
    }

    // Split-butterfly reduction: 32 partials/lane summed across 64 lanes in
    // 32 shuffles/lane. After 5 steps lane L's v[0] holds value index
    // h = bitrev5(L&31) summed over its 32-lane half; one xor-32 finishes.
    int v[32];
#pragma unroll
    for (int oo = 0; oo < 4; ++oo)
#pragma unroll
      for (int b = 0; b < 8; ++b) v[oo * 8 + b] = acc[oo][b];
#pragma unroll
    for (int s = 0; s < 5; ++s) {
      const int m = 1 << s;
      const int n = 16 >> s;
      const bool up = (lane & m) != 0;
#pragma unroll
      for (int i = 0; i < n; ++i) {
        int give = up ? v[i] : v[i + n];
        int keep = up ? v[i + n] : v[i];
        v[i] = keep + __shfl_xor(give, m);
      }
    }
    int tot = v[0] + __shfl_xor(v[0], 32);

    if (lane < 32) {
      int h = ((lane & 1) << 4) | ((lane & 2) << 2) | (lane & 4) |
              ((lane & 8) >> 2) | ((lane & 16) >> 4);
      int oo = h >> 3, b = h & 7;
      int o = o_base + oo;
      out[b * O_FEATS + o] =
          (float)(tot - s_sumx[b]) * s_scale + bias[o];
    }
  }
}

extern "C" void kernel_launch(void* const* d_in, const int* in_sizes, int n_in,
                              void* d_out, int out_size, void* d_ws, size_t ws_size,
                              hipStream_t stream) {
  const float* x = (const float*)d_in[0];
  const int* pw = (const int*)d_in[1];
  const float* wscale = (const float*)d_in[2];
  const float* bias = (const float*)d_in[3];
  float* out = (float*)d_out;
  uint32_t* ws = (uint32_t*)d_ws;

  k_absmax<<<64, 256, 0, stream>>>(x, ws);
  k_quant<<<64, 256, 0, stream>>>(x, ws);
  k_gemm<<<GRID, 256, 0, stream>>>(pw, wscale, bias, ws, out);
}